// Round 2
// 3907.039 us; speedup vs baseline: 3.9942x; 3.9942x over previous
//
#include <hip/hip_runtime.h>
#include <hip/hip_bf16.h>
#include <cstdint>
#include <cstddef>

// Problem dims
constexpr int Bz = 128, Tz = 25, Ez = 512, Hz = 1024, Vz = 10000, Fz = 2048;

__device__ __forceinline__ float sigm(float x) { return 1.f / (1.f + __expf(-x)); }
__device__ __forceinline__ float tanh_f(float x) {
    float e = __expf(-2.f * x);
    return 2.f / (1.f + e) - 1.f;
}
__device__ __forceinline__ float bf2f(unsigned short u) {
    return __builtin_bit_cast(float, ((unsigned)u) << 16);
}

// ---------------- dtype detector (bf16=1 / f32=0), from embedding halfwords ----
__global__ __launch_bounds__(256) void detect_k(const unsigned short* __restrict__ raw,
                                                int* __restrict__ flag) {
    __shared__ int sbuf[256];
    int tid = threadIdx.x, cnt = 0;
    for (int i = tid; i < 1024; i += 256) {
        unsigned short u = raw[2 * i];
        int e = (u >> 7) & 0xff;
        if (e >= 110 && e <= 127) cnt++;
    }
    sbuf[tid] = cnt;
    __syncthreads();
    for (int s = 128; s > 0; s >>= 1) {
        if (tid < s) sbuf[tid] += sbuf[tid + s];
        __syncthreads();
    }
    if (tid == 0) flag[0] = (sbuf[0] >= 512) ? 1 : 0;
}

__device__ __forceinline__ float ldf(const void* p, size_t i, int isbf) {
    return isbf ? bf2f(((const unsigned short*)p)[i]) : ((const float*)p)[i];
}

// ---------------- embedding gather -> f32 X0[t*128+b][e] ----------------
__global__ __launch_bounds__(256) void gatherf_k(const int* __restrict__ tok,
                                                 const void* __restrict__ emb,
                                                 float* __restrict__ X0,
                                                 const int* __restrict__ flag) {
    int idx = blockIdx.x * 256 + threadIdx.x;   // 3200*128 groups of 4
    if (idx >= 3200 * (Ez / 4)) return;
    int r = idx >> 7, c4 = (idx & 127) << 2;
    int t = r >> 7, b = r & 127;
    int tk = tok[b * Tz + t];
    int isbf = *flag;
    float4 o;
    o.x = ldf(emb, (size_t)tk * Ez + c4 + 0, isbf);
    o.y = ldf(emb, (size_t)tk * Ez + c4 + 1, isbf);
    o.z = ldf(emb, (size_t)tk * Ez + c4 + 2, isbf);
    o.w = ldf(emb, (size_t)tk * Ez + c4 + 3, isbf);
    *(float4*)(X0 + (size_t)r * Ez + c4) = o;
}

// ---------------- features -> f32 ----------------
__global__ __launch_bounds__(256) void convf_k(const void* __restrict__ in,
                                               float* __restrict__ out, int n,
                                               const int* __restrict__ flag) {
    int idx = blockIdx.x * 256 + threadIdx.x;
    if (idx >= n) return;
    out[idx] = ldf(in, idx, *flag);
}

// ---------------- bias pack to f32 ----------------
__global__ __launch_bounds__(256) void pack2_k(
    const void* __restrict__ bp,
    const void* __restrict__ bf0, const void* __restrict__ bi0,
    const void* __restrict__ bo0, const void* __restrict__ bg0,
    const void* __restrict__ bf1, const void* __restrict__ bi1,
    const void* __restrict__ bo1, const void* __restrict__ bg1,
    const void* __restrict__ bout,
    float* __restrict__ bp_f, float* __restrict__ b0_f, float* __restrict__ b1_f,
    float* __restrict__ bout_f, const int* __restrict__ flag) {
    int idx = blockIdx.x * 256 + threadIdx.x;
    int isbf = *flag;
    if (idx < 1024) {
        bp_f[idx] = ldf(bp, idx, isbf);
    } else if (idx < 5120) {
        int n = idx - 1024, g = n >> 10, j = n & 1023;
        const void* s = (g == 0) ? bf0 : (g == 1) ? bi0 : (g == 2) ? bo0 : bg0;
        b0_f[n] = ldf(s, j, isbf);
    } else if (idx < 9216) {
        int n = idx - 5120, g = n >> 10, j = n & 1023;
        const void* s = (g == 0) ? bf1 : (g == 1) ? bi1 : (g == 2) ? bo1 : bg1;
        b1_f[n] = ldf(s, j, isbf);
    } else if (idx < 9216 + Vz) {
        int n = idx - 9216;
        bout_f[n] = ldf(bout, n, isbf);
    }
}

// ---------------- LSTM cell elementwise, fused partial-sum (all f32) ----------
// parts: [P][128][4096] partial gate products; add: S0 row block or bias.
// col = gate*1024 + j, gate order f,i,o,g
__global__ __launch_bounds__(256) void cellP_k(const float* __restrict__ parts, int P,
                                               const float* __restrict__ add,
                                               int astride, int amask,
                                               float* __restrict__ c,
                                               float* __restrict__ d1, int ld1,
                                               float* __restrict__ d2, int ld2) {
    int idx = blockIdx.x * 256 + threadIdx.x;   // 131072
    int m = idx >> 10, j = idx & 1023;
    size_t ab = (size_t)(m & amask) * astride;
    float gf = add[ab + j];
    float gi = add[ab + 1024 + j];
    float go = add[ab + 2048 + j];
    float gg = add[ab + 3072 + j];
    size_t base = (size_t)m * 4096 + j;
    for (int p = 0; p < P; ++p) {
        const float* pp = parts + (size_t)p * 524288 + base;
        gf += pp[0];
        gi += pp[1024];
        go += pp[2048];
        gg += pp[3072];
    }
    float f = sigm(gf), ii = sigm(gi), o = sigm(go), g = tanh_f(gg);
    float cn = f * c[idx] + ii * g;
    c[idx] = cn;
    float h = o * tanh_f(cn);
    d1[(size_t)m * ld1 + j] = h;
    d2[(size_t)m * ld2 + j] = h;
}

// ---------------- partial-sum reducer (+bias, optional leaky) -----------------
template <int ACT>
__global__ __launch_bounds__(256) void sumP_k(const float* __restrict__ parts, int P,
                                              int Ns, const float* __restrict__ addv,
                                              int astride, int amask,
                                              float* __restrict__ out, int total) {
    int idx = blockIdx.x * 256 + threadIdx.x;
    if (idx >= total) return;
    int m = idx >> Ns, col = idx & ((1 << Ns) - 1);
    float v = addv[(size_t)(m & amask) * astride + col];
    for (int p = 0; p < P; ++p) v += parts[(size_t)p * total + idx];
    if (ACT == 1) v = (v > 0.f) ? v : 0.01f * v;
    out[idx] = v;
}

// =============================================================================
// Big GEMM: 128x128 macro-tile, 8x8 micro-tile (2x2 blocks of 4x4, 64 apart so
// every LDS frag read is a <=2-way-aliased ds_read_b128). Transposed-A LDS.
// Global->reg prefetch of next k-tile. C = A[M,K] @ B[rowoff:+K, :N] + addv.
// STORE: 0 = f32 to Cout[grow*ldc+gcol]; 2 = logits-permuted out[b][t][v].
// M % 128 == 0 required. N guarded.
// =============================================================================
template <int STORE, bool MULTI>
__global__ __launch_bounds__(256) void sgemm_big_k(
    const float* __restrict__ A, int lda,
    const void* __restrict__ B0, const void* __restrict__ B1,
    const void* __restrict__ B2, const void* __restrict__ B3,
    int ldb, int rowoff,
    const float* __restrict__ addv, int astride, int amask,
    void* __restrict__ Cout, int ldc, int N, int K,
    const int* __restrict__ flag) {
    __shared__ float As[16][132];   // [k][row] transposed
    __shared__ float Bs[16][132];   // [k][col]
    const int tid = threadIdx.x;
    const int tx = tid & 15, ty = tid >> 4;
    const int bn0 = blockIdx.x * 128, bm0 = blockIdx.y * 128;
    const int isbf = *flag;

    const int ar = tid >> 2;           // 0..63
    const int ac4 = (tid & 3) << 2;    // 0,4,8,12
    const int bk = tid >> 5;           // 0..7
    const int bn4 = (tid & 31) << 2;   // 0..124

    float acc[2][2][4][4];
#pragma unroll
    for (int mh = 0; mh < 2; mh++)
#pragma unroll
        for (int nh = 0; nh < 2; nh++)
#pragma unroll
            for (int i = 0; i < 4; i++)
#pragma unroll
                for (int j = 0; j < 4; j++) acc[mh][nh][i][j] = 0.f;

    float4 pa[2], pb[2];

    auto loadA = [&](int kt) {
#pragma unroll
        for (int it = 0; it < 2; ++it)
            pa[it] = *(const float4*)(A + (size_t)(bm0 + ar + it * 64) * lda + kt + ac4);
    };
    auto loadB = [&](int kt) {
#pragma unroll
        for (int it = 0; it < 2; ++it) {
            int kk = bk + it * 8;
            int ng = bn0 + bn4;
            float4 v = {0.f, 0.f, 0.f, 0.f};
            if (ng < N) {
                const void* bptr;
                int col;
                if constexpr (MULTI) {
                    int pi = ng >> 10;
                    bptr = (pi == 0) ? B0 : (pi == 1) ? B1 : (pi == 2) ? B2 : B3;
                    col = ng & 1023;
                } else {
                    bptr = B0;
                    col = ng;
                }
                size_t off = (size_t)(rowoff + kt + kk) * ldb + col;
                if (isbf) {
                    const unsigned short* us = (const unsigned short*)bptr + off;
                    v.x = bf2f(us[0]); v.y = bf2f(us[1]);
                    v.z = bf2f(us[2]); v.w = bf2f(us[3]);
                } else {
                    v = *(const float4*)((const float*)bptr + off);
                }
            }
            pb[it] = v;
        }
    };

    loadA(0);
    loadB(0);
    for (int kt = 0; kt < K; kt += 16) {
#pragma unroll
        for (int it = 0; it < 2; ++it) {
            int r = ar + it * 64;
            As[ac4 + 0][r] = pa[it].x;
            As[ac4 + 1][r] = pa[it].y;
            As[ac4 + 2][r] = pa[it].z;
            As[ac4 + 3][r] = pa[it].w;
            *(float4*)&Bs[bk + it * 8][bn4] = pb[it];
        }
        __syncthreads();
        if (kt + 16 < K) { loadA(kt + 16); loadB(kt + 16); }
#pragma unroll
        for (int kk = 0; kk < 16; ++kk) {
            float a[2][4], b[2][4];
            *(float4*)&a[0][0] = *(const float4*)&As[kk][ty * 4];
            *(float4*)&a[1][0] = *(const float4*)&As[kk][64 + ty * 4];
            *(float4*)&b[0][0] = *(const float4*)&Bs[kk][tx * 4];
            *(float4*)&b[1][0] = *(const float4*)&Bs[kk][64 + tx * 4];
#pragma unroll
            for (int mh = 0; mh < 2; ++mh)
#pragma unroll
                for (int i = 0; i < 4; ++i)
#pragma unroll
                    for (int nh = 0; nh < 2; ++nh)
#pragma unroll
                        for (int j = 0; j < 4; ++j)
                            acc[mh][nh][i][j] =
                                fmaf(a[mh][i], b[nh][j], acc[mh][nh][i][j]);
        }
        __syncthreads();
    }

#pragma unroll
    for (int mh = 0; mh < 2; ++mh)
#pragma unroll
        for (int i = 0; i < 4; ++i) {
            int grow = bm0 + mh * 64 + ty * 4 + i;
#pragma unroll
            for (int nh = 0; nh < 2; ++nh)
#pragma unroll
                for (int j = 0; j < 4; ++j) {
                    int gcol = bn0 + nh * 64 + tx * 4 + j;
                    if (gcol < N) {
                        float v = acc[mh][nh][i][j] +
                                  addv[(size_t)(grow & amask) * astride + gcol];
                        if (STORE == 0) {
                            ((float*)Cout)[(size_t)grow * ldc + gcol] = v;
                        } else {
                            int tt = grow >> 7, bb = grow & 127;
                            ((float*)Cout)[((size_t)(bb * Tz + tt)) * Vz + gcol] = v;
                        }
                    }
                }
        }
}

// =============================================================================
// Split-K partial GEMM for the small-M (M=128) recurrent GEMMs.
// 64x64 tile, 4x4 micro-tile, transposed-A LDS, all-b128 frag reads,
// global->reg prefetch. blockIdx.z = K-chunk; writes pure partial product to
// Cpart[z][128][N] (no addv). N % 64 == 0, KC % 16 == 0, M == 128.
// =============================================================================
template <bool MULTI>
__global__ __launch_bounds__(256) void sgemm_part_k(
    const float* __restrict__ A, int lda,
    const void* __restrict__ B0, const void* __restrict__ B1,
    const void* __restrict__ B2, const void* __restrict__ B3,
    int ldb, int rowoff,
    float* __restrict__ Cpart, int N, int KC,
    const int* __restrict__ flag) {
    __shared__ float As[16][68];   // [k][row] transposed
    __shared__ float Bs[16][68];   // [k][col]
    const int tid = threadIdx.x;
    const int tx = tid & 15, ty = tid >> 4;
    const int bn0 = blockIdx.x * 64, bm0 = blockIdx.y * 64;
    const int kbase = blockIdx.z * KC;
    const int isbf = *flag;

    const int ar = tid >> 2;           // 0..63
    const int ac4 = (tid & 3) << 2;    // 0,4,8,12
    const int bkk = tid >> 4;          // 0..15
    const int bn4 = (tid & 15) << 2;   // 0..60

    float acc[4][4];
#pragma unroll
    for (int i = 0; i < 4; i++)
#pragma unroll
        for (int j = 0; j < 4; j++) acc[i][j] = 0.f;

    float4 pa, pb;
    auto loadA = [&](int kt) {
        pa = *(const float4*)(A + (size_t)(bm0 + ar) * lda + kbase + kt + ac4);
    };
    auto loadB = [&](int kt) {
        int ng = bn0 + bn4;
        const void* bptr;
        int col;
        if constexpr (MULTI) {
            int pi = ng >> 10;
            bptr = (pi == 0) ? B0 : (pi == 1) ? B1 : (pi == 2) ? B2 : B3;
            col = ng & 1023;
        } else {
            bptr = B0;
            col = ng;
        }
        size_t off = (size_t)(rowoff + kbase + kt + bkk) * ldb + col;
        if (isbf) {
            const unsigned short* us = (const unsigned short*)bptr + off;
            pb.x = bf2f(us[0]); pb.y = bf2f(us[1]);
            pb.z = bf2f(us[2]); pb.w = bf2f(us[3]);
        } else {
            pb = *(const float4*)((const float*)bptr + off);
        }
    };

    loadA(0);
    loadB(0);
    for (int kt = 0; kt < KC; kt += 16) {
        As[ac4 + 0][ar] = pa.x;
        As[ac4 + 1][ar] = pa.y;
        As[ac4 + 2][ar] = pa.z;
        As[ac4 + 3][ar] = pa.w;
        *(float4*)&Bs[bkk][bn4] = pb;
        __syncthreads();
        if (kt + 16 < KC) { loadA(kt + 16); loadB(kt + 16); }
#pragma unroll
        for (int kk = 0; kk < 16; ++kk) {
            float a[4], b[4];
            *(float4*)&a[0] = *(const float4*)&As[kk][ty * 4];
            *(float4*)&b[0] = *(const float4*)&Bs[kk][tx * 4];
#pragma unroll
            for (int i = 0; i < 4; ++i)
#pragma unroll
                for (int j = 0; j < 4; ++j)
                    acc[i][j] = fmaf(a[i], b[j], acc[i][j]);
        }
        __syncthreads();
    }

    float* out = Cpart + (size_t)blockIdx.z * 128 * N;
#pragma unroll
    for (int i = 0; i < 4; ++i)
#pragma unroll
        for (int j = 0; j < 4; ++j)
            out[(size_t)(bm0 + ty * 4 + i) * N + bn0 + tx * 4 + j] = acc[i][j];
}

extern "C" void kernel_launch(void* const* d_in, const int* in_sizes, int n_in,
                              void* d_out, int out_size, void* d_ws, size_t ws_size,
                              hipStream_t stream) {
    const int* tokens = (const int*)d_in[0];
    const void* features = d_in[1];    // [128,2048]
    const void* embedding = d_in[2];   // [10000,512]
    const void* Wp = d_in[3];          // [2048,1024]
    const void* bp = d_in[4];
    const void* W0[4] = {d_in[5], d_in[7], d_in[9], d_in[11]};   // each [2560,1024]
    const void* b0[4] = {d_in[6], d_in[8], d_in[10], d_in[12]};
    const void* W1[4] = {d_in[13], d_in[15], d_in[17], d_in[19]}; // each [2048,1024]
    const void* b1[4] = {d_in[14], d_in[16], d_in[18], d_in[20]};
    const void* Wout = d_in[21];       // [1024,10000]
    const void* bout = d_in[22];

    char* w = (char*)d_ws;
    size_t cur = 0;
    auto alloc = [&](size_t bytes) {
        size_t o = cur;
        cur += (bytes + 255) & ~(size_t)255;
        return o;
    };
    float* X0f = (float*)(w + alloc((size_t)3200 * Ez * 4));     // [3200][512]
    float* featc = (float*)(w + alloc((size_t)Bz * Fz * 4));     // [128][2048]
    float* feat = (float*)(w + alloc((size_t)Bz * Hz * 4));      // [128][1024]
    float* Sfeat = (float*)(w + alloc((size_t)Bz * 4096 * 4));   // [128][4096]
    float* S0 = (float*)(w + alloc((size_t)3200 * 4096 * 4));    // [3200][4096] 50MB
    // zero-init block (contiguous): h0f, comb1f, c0, c1
    float* h0f = (float*)(w + alloc((size_t)Bz * Hz * 4));
    float* comb1f = (float*)(w + alloc((size_t)Bz * 2048 * 4));
    float* c0 = (float*)(w + alloc((size_t)Bz * Hz * 4));
    float* c1 = (float*)(w + alloc((size_t)Bz * Hz * 4));
    float* hsf = (float*)(w + alloc((size_t)3200 * Hz * 4));     // [3200][1024]
    float* parts = (float*)(w + alloc((size_t)4 * Bz * 4096 * 4)); // [4][128][4096]
    float* bp_f = (float*)(w + alloc(1024 * 4));
    float* b0_f = (float*)(w + alloc(4096 * 4));
    float* b1_f = (float*)(w + alloc(4096 * 4));
    float* bout_f = (float*)(w + alloc((size_t)Vz * 4));
    int* dflag = (int*)(w + alloc(256));
    (void)ws_size; (void)in_sizes; (void)n_in; (void)out_size;

    // 0) dtype detect (robustness; expected: f32 path)
    detect_k<<<1, 256, 0, stream>>>((const unsigned short*)embedding, dflag);

    // 1) biases, gather, features, state zero-init
    pack2_k<<<76, 256, 0, stream>>>(bp, b0[0], b0[1], b0[2], b0[3],
                                    b1[0], b1[1], b1[2], b1[3], bout,
                                    bp_f, b0_f, b1_f, bout_f, dflag);
    gatherf_k<<<1600, 256, 0, stream>>>(tokens, embedding, X0f, dflag);
    convf_k<<<1024, 256, 0, stream>>>(features, featc, Bz * Fz, dflag);
    hipMemsetAsync(h0f, 0,
                   (size_t)(Bz * Hz * 4 + Bz * 2048 * 4 + Bz * Hz * 4 + Bz * Hz * 4), stream);

    // 2) feat = leaky_relu(featc @ Wp + bp)   [128,1024] f32  (split-K P=4)
    sgemm_part_k<false><<<dim3(16, 2, 4), 256, 0, stream>>>(
        featc, Fz, Wp, Wp, Wp, Wp, Hz, 0, parts, 1024, 512, dflag);
    sumP_k<1><<<512, 256, 0, stream>>>(parts, 4, 10, bp_f, 0, 0, feat, Bz * Hz);

    // 3) Sfeat = feat @ W0[rows 512:1536] + b0   [128,4096] f32  (split-K P=4)
    sgemm_part_k<true><<<dim3(64, 2, 4), 256, 0, stream>>>(
        feat, Hz, W0[0], W0[1], W0[2], W0[3], Hz, 512, parts, 4096, 256, dflag);
    sumP_k<0><<<2048, 256, 0, stream>>>(parts, 4, 12, b0_f, 0, 0, Sfeat, Bz * 4096);

    // 4) S0 = X0 @ W0[rows 0:512] + Sfeat[row&127]   [3200,4096] f32 (big tiles)
    sgemm_big_k<0, true><<<dim3(32, 25), 256, 0, stream>>>(
        X0f, Ez, W0[0], W0[1], W0[2], W0[3], Hz, 0, Sfeat, 4096, 127,
        S0, 4096, 4096, Ez, dflag);

    // 5) time loop: split-K partial GEMMs (512 blocks each) + fused cell
    for (int t = 0; t < Tz; t++) {
        // parts = h0 @ W0[rows 1536:2560]  (K=1024, P=4, KC=256)
        sgemm_part_k<true><<<dim3(64, 2, 4), 256, 0, stream>>>(
            h0f, Hz, W0[0], W0[1], W0[2], W0[3], Hz, 1536, parts, 4096, 256, dflag);
        cellP_k<<<512, 256, 0, stream>>>(parts, 4, S0 + (size_t)t * Bz * 4096,
                                         4096, 127, c0, h0f, 1024, comb1f, 2048);
        // parts = [h0n | h1] @ W1  (K=2048, P=4, KC=512)
        sgemm_part_k<true><<<dim3(64, 2, 4), 256, 0, stream>>>(
            comb1f, 2048, W1[0], W1[1], W1[2], W1[3], Hz, 0, parts, 4096, 512, dflag);
        cellP_k<<<512, 256, 0, stream>>>(parts, 4, b1_f, 0, 0, c1,
                                         hsf + (size_t)t * Bz * Hz, 1024,
                                         comb1f + 1024, 2048);
    }

    // 6) logits = hs @ Wout + bout -> out[b][t][v] FLOAT32 (big tiles)
    sgemm_big_k<2, false><<<dim3(79, 25), 256, 0, stream>>>(
        hsf, Hz, Wout, Wout, Wout, Wout, Vz, 0, bout_f, 0, 0,
        d_out, Vz, Vz, Hz, dflag);
}